// Round 4
// baseline (413.162 us; speedup 1.0000x reference)
//
#include <hip/hip_runtime.h>

typedef __bf16 bf16_t;
typedef bf16_t bf16x8 __attribute__((ext_vector_type(8)));
typedef float f32x4 __attribute__((ext_vector_type(4)));

typedef const __attribute__((address_space(1))) void* as1_cvp;
typedef __attribute__((address_space(3))) void* as3_vp;

__device__ __forceinline__ void gload16(const void* g, void* l) {
  __builtin_amdgcn_global_load_lds((as1_cvp)g, (as3_vp)l, 16, 0, 0);
}

// ---------------------------------------------------------------- convert f32 -> bf16
__global__ __launch_bounds__(256) void cvt_kernel(const float* __restrict__ src,
                                                  bf16_t* __restrict__ dst, int n8) {
  int i = blockIdx.x * 256 + threadIdx.x;
  if (i >= n8) return;
  int idx = i * 8;
  float4 a = *(const float4*)(src + idx);
  float4 b = *(const float4*)(src + idx + 4);
  bf16x8 o;
  o[0] = (bf16_t)a.x; o[1] = (bf16_t)a.y; o[2] = (bf16_t)a.z; o[3] = (bf16_t)a.w;
  o[4] = (bf16_t)b.x; o[5] = (bf16_t)b.y; o[6] = (bf16_t)b.z; o[7] = (bf16_t)b.w;
  *(bf16x8*)(dst + idx) = o;
}

// ---------------------------------------------------------------- GEMM  C = A * B^T
// A: MxK bf16 row-major, B: NxK bf16 row-major (i.e. B^T input), C: MxN f32
// 128x128 tile, BK=64, 256 threads (4 waves, 2x2), m97 structure.
#define BM 128
#define BN 128
#define BK 64
__global__ __launch_bounds__(256, 2) void gemm_bt(const bf16_t* __restrict__ A,
                                                  const bf16_t* __restrict__ B,
                                                  float* __restrict__ C,
                                                  int M, int N, int K) {
  __shared__ alignas(16) bf16_t As[BM * BK];
  __shared__ alignas(16) bf16_t Bs[BN * BK];
  const int t = threadIdx.x;
  const int lane = t & 63, w = t >> 6;
  const int wm = w >> 1, wn = w & 1;
  const int lr = lane & 15, lg = lane >> 4;
  const int m0 = blockIdx.y * BM, n0 = blockIdx.x * BN;
  const int srow = t >> 3, scol = (t & 7) * 8;  // staging: row within 32-group, col chunk

  f32x4 acc[4][4] = {};

  for (int kb = 0; kb < K; kb += BK) {
    __syncthreads();
#pragma unroll
    for (int i = 0; i < 4; ++i) {
      gload16(A + (size_t)(m0 + srow + 32 * i) * K + kb + scol, As + i * 2048 + t * 8);
      gload16(B + (size_t)(n0 + srow + 32 * i) * K + kb + scol, Bs + i * 2048 + t * 8);
    }
    __syncthreads();
#pragma unroll
    for (int kk = 0; kk < 2; ++kk) {
      const int ko = kk * 32 + lg * 8;
      bf16x8 af[4], bfr[4];
#pragma unroll
      for (int r = 0; r < 4; ++r)
        af[r] = *(const bf16x8*)(As + (wm * 64 + r * 16 + lr) * BK + ko);
#pragma unroll
      for (int c = 0; c < 4; ++c)
        bfr[c] = *(const bf16x8*)(Bs + (wn * 64 + c * 16 + lr) * BK + ko);
#pragma unroll
      for (int r = 0; r < 4; ++r)
#pragma unroll
        for (int c = 0; c < 4; ++c)
          acc[r][c] = __builtin_amdgcn_mfma_f32_16x16x32_bf16(af[r], bfr[c], acc[r][c], 0, 0, 0);
    }
  }
  // epilogue: D layout row=(lane>>4)*4+b, col=lane&15
#pragma unroll
  for (int r = 0; r < 4; ++r)
#pragma unroll
    for (int c = 0; c < 4; ++c)
#pragma unroll
      for (int b = 0; b < 4; ++b)
        C[(size_t)(m0 + wm * 64 + r * 16 + lg * 4 + b) * N + n0 + wn * 64 + c * 16 + lr] =
            acc[r][c][b];
}

// ---------------------------------------------------------------- RoPE + relayout (Q or K)
// src: qkv f32 (4096 x 3072), dst: (B, nh, S, HD) bf16
__global__ __launch_bounds__(256) void rope_kernel(const float* __restrict__ qkv,
                                                   const float* __restrict__ cs,
                                                   const float* __restrict__ sn,
                                                   bf16_t* __restrict__ dst,
                                                   int nh, int lognh, int col_off) {
  int idx = blockIdx.x * 256 + threadIdx.x;
  int chunk = idx & 15;            // 16 chunks of 8 elems (=4 pairs) over HD=128
  int s = (idx >> 4) & 2047;
  int hh = (idx >> 15) & (nh - 1);
  int bb = idx >> (15 + lognh);
  const float* src = qkv + (size_t)(bb * 2048 + s) * 3072 + col_off + hh * 128 + chunk * 8;
  float4 x0 = *(const float4*)src;
  float4 x1 = *(const float4*)(src + 4);
  float4 c4 = *(const float4*)(cs + s * 64 + chunk * 4);
  float4 s4 = *(const float4*)(sn + s * 64 + chunk * 4);
  bf16x8 o;
  o[0] = (bf16_t)(x0.x * c4.x - x0.y * s4.x);
  o[1] = (bf16_t)(x0.x * s4.x + x0.y * c4.x);
  o[2] = (bf16_t)(x0.z * c4.y - x0.w * s4.y);
  o[3] = (bf16_t)(x0.z * s4.y + x0.w * c4.y);
  o[4] = (bf16_t)(x1.x * c4.z - x1.y * s4.z);
  o[5] = (bf16_t)(x1.x * s4.z + x1.y * c4.z);
  o[6] = (bf16_t)(x1.z * c4.w - x1.w * s4.w);
  o[7] = (bf16_t)(x1.z * s4.w + x1.w * c4.w);
  *(bf16x8*)(dst + ((size_t)(bb * nh + hh) * 2048 + s) * 128 + chunk * 8) = o;
}

// ---------------------------------------------------------------- V transpose: (B,S,[v cols]) -> (B,NKV,HD,S) bf16
__global__ __launch_bounds__(256) void vt_kernel(const float* __restrict__ qkv,
                                                 bf16_t* __restrict__ vt) {
  __shared__ bf16_t tile[64][128];
  int t = threadIdx.x;
  int bid = blockIdx.x;  // (bb*4 + kh)*32 + st
  int st = bid & 31;
  int kh = (bid >> 5) & 3;
  int bb = bid >> 7;
  const float* src = qkv + (size_t)(bb * 2048 + st * 64) * 3072 + 2560 + kh * 128;
#pragma unroll
  for (int j = 0; j < 8; ++j) {
    int id = t + 256 * j;  // 2048 float4 chunks: 64 rows x 32 fvec
    int sr = id >> 5, dv = id & 31;
    float4 x = *(const float4*)(src + (size_t)sr * 3072 + dv * 4);
    tile[sr][dv * 4 + 0] = (bf16_t)x.x;
    tile[sr][dv * 4 + 1] = (bf16_t)x.y;
    tile[sr][dv * 4 + 2] = (bf16_t)x.z;
    tile[sr][dv * 4 + 3] = (bf16_t)x.w;
  }
  __syncthreads();
  bf16_t* dst = vt + (size_t)(bb * 4 + kh) * 128 * 2048 + st * 64;
#pragma unroll
  for (int j = 0; j < 4; ++j) {
    int id = t + 256 * j;  // 1024 chunks of 8 bf16: 128 d x 8 s-chunks
    int d = id >> 3, sc8 = id & 7;
    bf16x8 v;
#pragma unroll
    for (int e = 0; e < 8; ++e) v[e] = tile[sc8 * 8 + e][d];
    *(bf16x8*)(dst + (size_t)d * 2048 + sc8 * 8) = v;
  }
}

// ---------------------------------------------------------------- flash attention
// Q:(B,NH,S,HD) K:(B,NKV,S,HD) Vt:(B,NKV,HD,S) all bf16 -> O:(B*S, H) bf16
// 4 waves/block, 16 q-rows/wave (QBLK=64); K double-buffered in LDS (2-phase),
// V read DIRECTLY from global (L2/L3-resident; frees 32KB LDS -> 4 blocks/CU).
// XOR-swizzled K/P LDS (rule #21). T13 defer-rescale, T5 setprio,
// per-lane deferred l-sum (reduced once in epilogue).
#define KVB 64
__global__ __launch_bounds__(256, 4) void attn_kernel(const bf16_t* __restrict__ Q,
                                                      const bf16_t* __restrict__ Kg,
                                                      const bf16_t* __restrict__ Vg,
                                                      bf16_t* __restrict__ O) {
  __shared__ alignas(16) bf16_t Ks[2][KVB * 128];   // 32KB [key][d], swizzled
  __shared__ alignas(16) bf16_t Ps[4][16 * KVB];    // 8KB  per-wave P [q][key], swizzled
  const int t = threadIdx.x;
  const int lane = t & 63, w = t >> 6;
  const int lr = lane & 15, lg = lane >> 4;
  const int swz = (lr & 7) * 8;  // read-side XOR (row&7 == lr&7 for all fragment reads)
  const int bid = blockIdx.x;
  const int qt = bid & 31;
  const int h = (bid >> 5) & 15;
  const int bb = bid >> 9;
  const int kvh = h >> 2;

  const bf16_t* Qh = Q + (((size_t)bb * 16 + h) * 2048 + qt * 64 + w * 16) * 128;
  const bf16_t* Kh = Kg + ((size_t)bb * 4 + kvh) * 2048 * 128;
  const bf16_t* Vh = Vg + ((size_t)bb * 4 + kvh) * 128 * 2048;

  // K staging source indices (pre-swizzled chunk within each row)
  const int krow = t >> 4;                       // 0..15 (16 K-rows per i-group)
  const int kcs = ((t & 15) ^ (krow & 7)) * 8;   // swizzled col chunk, 128-elem row

  // hoist Q fragments (16 rows x 128 d)
  bf16x8 qf[4];
#pragma unroll
  for (int kc = 0; kc < 4; ++kc)
    qf[kc] = *(const bf16x8*)(Qh + lr * 128 + kc * 32 + lg * 8);

  f32x4 o[8] = {};
  float m2[4] = {-1e30f, -1e30f, -1e30f, -1e30f};
  float ls[4] = {0.f, 0.f, 0.f, 0.f};  // per-lane partial sums (reduced in epilogue)
  const float sm = 0.08838834764831845f * 1.44269504088896f;  // 1/sqrt(128) * log2(e)

#define STAGE(buf, kb)                                                                    \
  _Pragma("unroll") for (int i = 0; i < 4; ++i) {                                         \
    gload16(Kh + (size_t)((kb) + i * 16 + krow) * 128 + kcs, &Ks[buf][i * 2048 + t * 8]); \
  }

  STAGE(0, 0);
  __syncthreads();

  for (int tt = 0; tt < 32; ++tt) {
    const int cur = tt & 1;
    const int kb = tt * KVB;
    if (tt < 31) { STAGE(cur ^ 1, kb + KVB); }
    const bf16_t* Kc = Ks[cur];

    // QK^T: 4 col-groups x 4 k-chunks
    f32x4 sc[4];
    __builtin_amdgcn_s_setprio(1);
#pragma unroll
    for (int cg = 0; cg < 4; ++cg) {
      f32x4 a = {};
#pragma unroll
      for (int kc = 0; kc < 4; ++kc) {
        bf16x8 kf = *(const bf16x8*)(Kc + (cg * 16 + lr) * 128 + ((kc * 32 + lg * 8) ^ swz));
        a = __builtin_amdgcn_mfma_f32_16x16x32_bf16(qf[kc], kf, a, 0, 0, 0);
      }
      sc[cg] = a * sm;  // log2 units
    }
    __builtin_amdgcn_s_setprio(0);

    // online softmax (rows live in 16-lane groups; masks 1,2,4,8 stay in-group)
    float mx[4];
#pragma unroll
    for (int b = 0; b < 4; ++b) {
      float v = fmaxf(fmaxf(sc[0][b], sc[1][b]), fmaxf(sc[2][b], sc[3][b]));
      v = fmaxf(v, __shfl_xor(v, 1));
      v = fmaxf(v, __shfl_xor(v, 2));
      v = fmaxf(v, __shfl_xor(v, 4));
      v = fmaxf(v, __shfl_xor(v, 8));
      mx[b] = v;
    }
    // T13: rescale only if some row's max grew by > 8 (log2) -> P bounded by 256
    bool need = false;
#pragma unroll
    for (int b = 0; b < 4; ++b) need = need || (mx[b] > m2[b] + 8.0f);
    if (__any(need)) {
#pragma unroll
      for (int b = 0; b < 4; ++b) {
        float mn = fmaxf(m2[b], mx[b]);
        float resc = exp2f(m2[b] - mn);
        m2[b] = mn;
        ls[b] *= resc;
#pragma unroll
        for (int d = 0; d < 8; ++d) o[d][b] *= resc;
      }
    }
#pragma unroll
    for (int cg = 0; cg < 4; ++cg)
#pragma unroll
      for (int b = 0; b < 4; ++b) {
        float p = exp2f(sc[cg][b] - m2[b]);
        sc[cg][b] = p;
        ls[b] += p;  // per-lane partial; cross-lane reduce deferred to epilogue
      }

    // P: D-layout -> LDS row-major [16][64] (wave-private), swizzled by row&7
    bf16_t* P = Ps[w];
#pragma unroll
    for (int cg = 0; cg < 4; ++cg)
#pragma unroll
      for (int b = 0; b < 4; ++b) {
        int prow = lg * 4 + b;
        P[prow * KVB + ((cg * 16 + lr) ^ ((prow & 7) * 8))] = (bf16_t)sc[cg][b];
      }

    bf16x8 pf[2];
#pragma unroll
    for (int kk = 0; kk < 2; ++kk)   // P row = lr -> row&7 == lr&7
      pf[kk] = *(const bf16x8*)(P + lr * KVB + ((kk * 32 + lg * 8) ^ swz));

    // PV: V fragments straight from global (L2-resident, addresses independent
    // of softmax -> loads hoist/overlap)
    __builtin_amdgcn_s_setprio(1);
#pragma unroll
    for (int d = 0; d < 8; ++d) {
#pragma unroll
      for (int kk = 0; kk < 2; ++kk) {
        bf16x8 vf = *(const bf16x8*)(Vh + (size_t)(d * 16 + lr) * 2048 + kb + kk * 32 + lg * 8);
        o[d] = __builtin_amdgcn_mfma_f32_16x16x32_bf16(pf[kk], vf, o[d], 0, 0, 0);
      }
    }
    __builtin_amdgcn_s_setprio(0);
    __syncthreads();  // drains vmcnt -> next K tile ready; P reads done for rewrite
  }

  // epilogue: reduce l across the 16-lane row group, divide, write (B*S, H) bf16
#pragma unroll
  for (int b = 0; b < 4; ++b) {
    float v = ls[b];
    v += __shfl_xor(v, 1);
    v += __shfl_xor(v, 2);
    v += __shfl_xor(v, 4);
    v += __shfl_xor(v, 8);
    ls[b] = v;
  }
  const size_t q0 = (size_t)bb * 2048 + qt * 64 + w * 16;
#pragma unroll
  for (int d = 0; d < 8; ++d)
#pragma unroll
    for (int b = 0; b < 4; ++b) {
      float val = o[d][b] / ls[b];
      O[(q0 + lg * 4 + b) * 2048 + h * 128 + d * 16 + lr] = (bf16_t)val;
    }
}

// ---------------------------------------------------------------- launch
extern "C" void kernel_launch(void* const* d_in, const int* in_sizes, int n_in,
                              void* d_out, int out_size, void* d_ws, size_t ws_size,
                              hipStream_t stream) {
  const float* hs = (const float*)d_in[0];
  const float* fc = (const float*)d_in[1];
  const float* fs = (const float*)d_in[2];
  const float* Wq = (const float*)d_in[3];
  const float* Wk = (const float*)d_in[4];
  const float* Wv = (const float*)d_in[5];
  const float* Wo = (const float*)d_in[6];
  float* out = (float*)d_out;

  char* ws = (char*)d_ws;
  bf16_t* hs_b = (bf16_t*)ws;                      // 16,777,216 B
  bf16_t* wcat = (bf16_t*)(ws + 16777216);         // 12,582,912 B (3072x2048)
  bf16_t* wo_b = (bf16_t*)(ws + 29360128);         //  8,388,608 B
  float* qkv = (float*)(ws + 37748736);            // 50,331,648 B (4096x3072)
  bf16_t* qr = (bf16_t*)(ws + 88080384);           // 16,777,216 B
  bf16_t* kr = (bf16_t*)(ws + 104857600);          //  4,194,304 B
  bf16_t* vt = (bf16_t*)(ws + 109051904);          //  4,194,304 B
  bf16_t* ao = (bf16_t*)(ws + 113246208);          // 16,777,216 B  (total ~124 MB)

  cvt_kernel<<<8388608 / 8 / 256, 256, 0, stream>>>(hs, hs_b, 8388608 / 8);
  cvt_kernel<<<4194304 / 8 / 256, 256, 0, stream>>>(Wq, wcat, 4194304 / 8);
  cvt_kernel<<<1048576 / 8 / 256, 256, 0, stream>>>(Wk, wcat + 4194304, 1048576 / 8);
  cvt_kernel<<<1048576 / 8 / 256, 256, 0, stream>>>(Wv, wcat + 5242880, 1048576 / 8);
  cvt_kernel<<<4194304 / 8 / 256, 256, 0, stream>>>(Wo, wo_b, 4194304 / 8);

  dim3 g1(3072 / BN, 4096 / BM);
  gemm_bt<<<g1, 256, 0, stream>>>(hs_b, wcat, qkv, 4096, 3072, 2048);

  rope_kernel<<<4096, 256, 0, stream>>>(qkv, fc, fs, qr, 16, 4, 0);
  rope_kernel<<<1024, 256, 0, stream>>>(qkv, fc, fs, kr, 4, 2, 2048);
  vt_kernel<<<256, 256, 0, stream>>>(qkv, vt);

  attn_kernel<<<1024, 256, 0, stream>>>(qr, kr, vt, ao);

  dim3 g2(2048 / BN, 4096 / BM);
  gemm_bt<<<g2, 256, 0, stream>>>(ao, wo_b, out, 4096, 2048, 2048);
}

// Round 5
// 299.506 us; speedup vs baseline: 1.3795x; 1.3795x over previous
//
#include <hip/hip_runtime.h>

typedef __bf16 bf16_t;
typedef bf16_t bf16x8 __attribute__((ext_vector_type(8)));
typedef bf16_t bf16x2 __attribute__((ext_vector_type(2)));
typedef float f32x4 __attribute__((ext_vector_type(4)));
typedef unsigned int u32x4 __attribute__((ext_vector_type(4)));

typedef const __attribute__((address_space(1))) void* as1_cvp;
typedef __attribute__((address_space(3))) void* as3_vp;

__device__ __forceinline__ void gload16(const void* g, void* l) {
  __builtin_amdgcn_global_load_lds((as1_cvp)g, (as3_vp)l, 16, 0, 0);
}

// ---------------------------------------------------------------- convert f32 -> bf16
__global__ __launch_bounds__(256) void cvt_kernel(const float* __restrict__ src,
                                                  bf16_t* __restrict__ dst, int n8) {
  int i = blockIdx.x * 256 + threadIdx.x;
  if (i >= n8) return;
  int idx = i * 8;
  float4 a = *(const float4*)(src + idx);
  float4 b = *(const float4*)(src + idx + 4);
  bf16x8 o;
  o[0] = (bf16_t)a.x; o[1] = (bf16_t)a.y; o[2] = (bf16_t)a.z; o[3] = (bf16_t)a.w;
  o[4] = (bf16_t)b.x; o[5] = (bf16_t)b.y; o[6] = (bf16_t)b.z; o[7] = (bf16_t)b.w;
  *(bf16x8*)(dst + idx) = o;
}

// ---------------------------------------------------------------- GEMM  C = A * B^T
// A: MxK bf16 row-major, B: NxK bf16 row-major (i.e. B^T input), C: MxN f32
// 128x128 tile, BK=64, 256 threads (4 waves, 2x2), m97 structure.
#define BM 128
#define BN 128
#define BK 64
__global__ __launch_bounds__(256, 2) void gemm_bt(const bf16_t* __restrict__ A,
                                                  const bf16_t* __restrict__ B,
                                                  float* __restrict__ C,
                                                  int M, int N, int K) {
  __shared__ alignas(16) bf16_t As[BM * BK];
  __shared__ alignas(16) bf16_t Bs[BN * BK];
  const int t = threadIdx.x;
  const int lane = t & 63, w = t >> 6;
  const int wm = w >> 1, wn = w & 1;
  const int lr = lane & 15, lg = lane >> 4;
  const int m0 = blockIdx.y * BM, n0 = blockIdx.x * BN;
  const int srow = t >> 3, scol = (t & 7) * 8;  // staging: row within 32-group, col chunk

  f32x4 acc[4][4] = {};

  for (int kb = 0; kb < K; kb += BK) {
    __syncthreads();
#pragma unroll
    for (int i = 0; i < 4; ++i) {
      gload16(A + (size_t)(m0 + srow + 32 * i) * K + kb + scol, As + i * 2048 + t * 8);
      gload16(B + (size_t)(n0 + srow + 32 * i) * K + kb + scol, Bs + i * 2048 + t * 8);
    }
    __syncthreads();
#pragma unroll
    for (int kk = 0; kk < 2; ++kk) {
      const int ko = kk * 32 + lg * 8;
      bf16x8 af[4], bfr[4];
#pragma unroll
      for (int r = 0; r < 4; ++r)
        af[r] = *(const bf16x8*)(As + (wm * 64 + r * 16 + lr) * BK + ko);
#pragma unroll
      for (int c = 0; c < 4; ++c)
        bfr[c] = *(const bf16x8*)(Bs + (wn * 64 + c * 16 + lr) * BK + ko);
#pragma unroll
      for (int r = 0; r < 4; ++r)
#pragma unroll
        for (int c = 0; c < 4; ++c)
          acc[r][c] = __builtin_amdgcn_mfma_f32_16x16x32_bf16(af[r], bfr[c], acc[r][c], 0, 0, 0);
    }
  }
  // epilogue: D layout row=(lane>>4)*4+b, col=lane&15
#pragma unroll
  for (int r = 0; r < 4; ++r)
#pragma unroll
    for (int c = 0; c < 4; ++c)
#pragma unroll
      for (int b = 0; b < 4; ++b)
        C[(size_t)(m0 + wm * 64 + r * 16 + lg * 4 + b) * N + n0 + wn * 64 + c * 16 + lr] =
            acc[r][c][b];
}

// ---------------------------------------------------------------- RoPE + relayout (Q or K)
// src: qkv f32 (4096 x 3072), dst: (B, nh, S, HD) bf16
__global__ __launch_bounds__(256) void rope_kernel(const float* __restrict__ qkv,
                                                   const float* __restrict__ cs,
                                                   const float* __restrict__ sn,
                                                   bf16_t* __restrict__ dst,
                                                   int nh, int lognh, int col_off) {
  int idx = blockIdx.x * 256 + threadIdx.x;
  int chunk = idx & 15;            // 16 chunks of 8 elems (=4 pairs) over HD=128
  int s = (idx >> 4) & 2047;
  int hh = (idx >> 15) & (nh - 1);
  int bb = idx >> (15 + lognh);
  const float* src = qkv + (size_t)(bb * 2048 + s) * 3072 + col_off + hh * 128 + chunk * 8;
  float4 x0 = *(const float4*)src;
  float4 x1 = *(const float4*)(src + 4);
  float4 c4 = *(const float4*)(cs + s * 64 + chunk * 4);
  float4 s4 = *(const float4*)(sn + s * 64 + chunk * 4);
  bf16x8 o;
  o[0] = (bf16_t)(x0.x * c4.x - x0.y * s4.x);
  o[1] = (bf16_t)(x0.x * s4.x + x0.y * c4.x);
  o[2] = (bf16_t)(x0.z * c4.y - x0.w * s4.y);
  o[3] = (bf16_t)(x0.z * s4.y + x0.w * c4.y);
  o[4] = (bf16_t)(x1.x * c4.z - x1.y * s4.z);
  o[5] = (bf16_t)(x1.x * s4.z + x1.y * c4.z);
  o[6] = (bf16_t)(x1.z * c4.w - x1.w * s4.w);
  o[7] = (bf16_t)(x1.z * s4.w + x1.w * c4.w);
  *(bf16x8*)(dst + ((size_t)(bb * nh + hh) * 2048 + s) * 128 + chunk * 8) = o;
}

// ---------------------------------------------------------------- V transpose: (B,S,[v cols]) -> (B,NKV,HD,S) bf16
__global__ __launch_bounds__(256) void vt_kernel(const float* __restrict__ qkv,
                                                 bf16_t* __restrict__ vt) {
  __shared__ bf16_t tile[64][128];
  int t = threadIdx.x;
  int bid = blockIdx.x;  // (bb*4 + kh)*32 + st
  int st = bid & 31;
  int kh = (bid >> 5) & 3;
  int bb = bid >> 7;
  const float* src = qkv + (size_t)(bb * 2048 + st * 64) * 3072 + 2560 + kh * 128;
#pragma unroll
  for (int j = 0; j < 8; ++j) {
    int id = t + 256 * j;  // 2048 float4 chunks: 64 rows x 32 fvec
    int sr = id >> 5, dv = id & 31;
    float4 x = *(const float4*)(src + (size_t)sr * 3072 + dv * 4);
    tile[sr][dv * 4 + 0] = (bf16_t)x.x;
    tile[sr][dv * 4 + 1] = (bf16_t)x.y;
    tile[sr][dv * 4 + 2] = (bf16_t)x.z;
    tile[sr][dv * 4 + 3] = (bf16_t)x.w;
  }
  __syncthreads();
  bf16_t* dst = vt + (size_t)(bb * 4 + kh) * 128 * 2048 + st * 64;
#pragma unroll
  for (int j = 0; j < 4; ++j) {
    int id = t + 256 * j;  // 1024 chunks of 8 bf16: 128 d x 8 s-chunks
    int d = id >> 3, sc8 = id & 7;
    bf16x8 v;
#pragma unroll
    for (int e = 0; e < 8; ++e) v[e] = tile[sc8 * 8 + e][d];
    *(bf16x8*)(dst + (size_t)d * 2048 + sc8 * 8) = v;
  }
}

// ---------------------------------------------------------------- flash attention
// Q:(B,NH,S,HD) K:(B,NKV,S,HD) Vt:(B,NKV,HD,S) all bf16 -> O:(B*S, H) bf16
// 4 waves/block, 16 q-rows/wave (QBLK=64). K double-buffered (2-phase prefetch),
// V single-buffered (staged at tile top, covered by QK^T+softmax). 48KB LDS ->
// 3 blocks/CU. Swapped QK^T (mfma(K,Q)) puts q=lane&15: softmax fully
// in-register (scalar m/ls per lane, 2-shfl row reduce), P redistributed to
// A-fragment layout via 16 shfl + 8 selects (no P LDS roundtrip).
// XOR-swizzled K/V LDS (rule #21). T13 defer-rescale, T5 setprio.
#define KVB 64
__global__ __launch_bounds__(256, 3) void attn_kernel(const bf16_t* __restrict__ Q,
                                                      const bf16_t* __restrict__ Kg,
                                                      const bf16_t* __restrict__ Vg,
                                                      bf16_t* __restrict__ O) {
  __shared__ alignas(16) bf16_t Ks[2][KVB * 128];   // 32KB [key][d], swizzled
  __shared__ alignas(16) bf16_t Vs[128 * KVB];      // 16KB [d][key], swizzled
  const int t = threadIdx.x;
  const int lane = t & 63, w = t >> 6;
  const int lr = lane & 15, lg = lane >> 4;
  const int swz = (lr & 7) * 8;  // read-side XOR (row&7 == lr&7 for all fragment reads)
  const int bid = blockIdx.x;
  const int qt = bid & 31;
  const int h = (bid >> 5) & 15;
  const int bb = bid >> 9;
  const int kvh = h >> 2;

  const bf16_t* Qh = Q + (((size_t)bb * 16 + h) * 2048 + qt * 64 + w * 16) * 128;
  const bf16_t* Kh = Kg + ((size_t)bb * 4 + kvh) * 2048 * 128;
  const bf16_t* Vh = Vg + ((size_t)bb * 4 + kvh) * 128 * 2048;

  // staging source indices (pre-swizzled chunk within each row)
  const int krow = t >> 4;                       // 0..15 (16 K-rows per i-group)
  const int kcs = ((t & 15) ^ (krow & 7)) * 8;   // swizzled col chunk, 128-elem row
  const int vrow = t >> 3;                       // 0..31 (32 V-rows per i-group)
  const int vcs = ((t & 7) ^ (vrow & 7)) * 8;    // swizzled col chunk, 64-elem row

  // hoist Q fragments (16 rows x 128 d); used as the MFMA *B* operand
  bf16x8 qf[4];
#pragma unroll
  for (int kc = 0; kc < 4; ++kc)
    qf[kc] = *(const bf16x8*)(Qh + lr * 128 + kc * 32 + lg * 8);

  f32x4 o[8] = {};
  float m2 = -1e30f;  // running max for row q=lr (replicated across the 4 lg lanes)
  float ls = 0.f;     // per-lane partial sum over this lane's 16 k-slots
  const float sm = 0.08838834764831845f * 1.44269504088896f;  // 1/sqrt(128) * log2(e)

#define STAGE_K(buf, kb)                                                                  \
  _Pragma("unroll") for (int i = 0; i < 4; ++i) {                                         \
    gload16(Kh + (size_t)((kb) + i * 16 + krow) * 128 + kcs, &Ks[buf][i * 2048 + t * 8]); \
  }
#define STAGE_V(kb)                                                                       \
  _Pragma("unroll") for (int i = 0; i < 4; ++i) {                                         \
    gload16(Vh + (size_t)(i * 32 + vrow) * 2048 + (kb) + vcs, &Vs[i * 2048 + t * 8]);     \
  }

  STAGE_K(0, 0);
  __syncthreads();  // K(0) arrived

  for (int tt = 0; tt < 32; ++tt) {
    const int cur = tt & 1;
    const int kb = tt * KVB;
    STAGE_V(kb);                                    // V(t): covered by QK^T+softmax
    if (tt < 31) { STAGE_K(cur ^ 1, kb + KVB); }    // K(t+1): covered by full tile
    const bf16_t* Kc = Ks[cur];

    // Swapped QK^T: D[k][q] -> lane(lr,lg) holds P[q=lr][k=cg*16+lg*4+b]
    f32x4 sc[4];
    __builtin_amdgcn_s_setprio(1);
#pragma unroll
    for (int cg = 0; cg < 4; ++cg) {
      f32x4 a = {};
#pragma unroll
      for (int kc = 0; kc < 4; ++kc) {
        bf16x8 kf = *(const bf16x8*)(Kc + (cg * 16 + lr) * 128 + ((kc * 32 + lg * 8) ^ swz));
        a = __builtin_amdgcn_mfma_f32_16x16x32_bf16(kf, qf[kc], a, 0, 0, 0);
      }
      sc[cg] = a * sm;  // log2 units
    }
    __builtin_amdgcn_s_setprio(0);

    // row max: 15 in-lane fmax + 2 shfl (across the 4 lg lanes of row lr)
    float mx = fmaxf(fmaxf(fmaxf(sc[0][0], sc[0][1]), fmaxf(sc[0][2], sc[0][3])),
                     fmaxf(fmaxf(sc[1][0], sc[1][1]), fmaxf(sc[1][2], sc[1][3])));
    mx = fmaxf(mx, fmaxf(fmaxf(fmaxf(sc[2][0], sc[2][1]), fmaxf(sc[2][2], sc[2][3])),
                         fmaxf(fmaxf(sc[3][0], sc[3][1]), fmaxf(sc[3][2], sc[3][3]))));
    mx = fmaxf(mx, __shfl_xor(mx, 16));
    mx = fmaxf(mx, __shfl_xor(mx, 32));

    // T13: rescale only if max grew by > 8 (log2) -> P bounded by 256
    if (__any(mx > m2 + 8.0f)) {
      float mn = fmaxf(m2, mx);
      float resc = exp2f(m2 - mn);
      m2 = mn;
      ls *= resc;
      float rb[4];
#pragma unroll
      for (int b = 0; b < 4; ++b) rb[b] = __shfl(resc, lg * 4 + b);  // to o-row layout
#pragma unroll
      for (int d = 0; d < 8; ++d)
#pragma unroll
        for (int b = 0; b < 4; ++b) o[d][b] *= rb[b];
    }
    // exp + partial sum (this lane's 16 k-slots of row lr)
#pragma unroll
    for (int cg = 0; cg < 4; ++cg)
#pragma unroll
      for (int b = 0; b < 4; ++b) {
        float p = exp2f(sc[cg][b] - m2);
        sc[cg][b] = p;
        ls += p;
      }

    // pack to bf16 pairs: W[cg*2+h] = {P[k=cg*16+lg*4+2h], P[..+2h+1]}
    unsigned W[8];
#pragma unroll
    for (int cg = 0; cg < 4; ++cg)
#pragma unroll
      for (int hh2 = 0; hh2 < 2; ++hh2) {
        bf16x2 pr = {(bf16_t)sc[cg][2 * hh2], (bf16_t)sc[cg][2 * hh2 + 1]};
        W[cg * 2 + hh2] = __builtin_bit_cast(unsigned, pr);
      }
    // redistribute to A-frag: lane(lr,lg) word m of chunk kk holds k=kk*32+lg*8+2m..+2m+1
    // src lane = (lr, 2*(lg&1) + (m>>1)); src word = W[(2*kk + (lg>>1))*2 + (m&1)]
    u32x4 pw[2];
#pragma unroll
    for (int kk = 0; kk < 2; ++kk)
#pragma unroll
      for (int m = 0; m < 4; ++m) {
        int srcl = lr + 16 * (2 * (lg & 1) + (m >> 1));
        int t0 = __shfl((int)W[(2 * kk) * 2 + (m & 1)], srcl);
        int t1 = __shfl((int)W[(2 * kk + 1) * 2 + (m & 1)], srcl);
        pw[kk][m] = (unsigned)((lg & 2) ? t1 : t0);
      }
    bf16x8 pf0 = __builtin_bit_cast(bf16x8, pw[0]);
    bf16x8 pf1 = __builtin_bit_cast(bf16x8, pw[1]);

    __syncthreads();  // #1: V(t) arrived (drains vmcnt)

    // PV: o[q=lg*4+b][d=dblk*16+lr]
    __builtin_amdgcn_s_setprio(1);
#pragma unroll
    for (int d = 0; d < 8; ++d) {
      bf16x8 vf0 = *(const bf16x8*)(Vs + (d * 16 + lr) * KVB + ((0 * 32 + lg * 8) ^ swz));
      o[d] = __builtin_amdgcn_mfma_f32_16x16x32_bf16(pf0, vf0, o[d], 0, 0, 0);
      bf16x8 vf1 = *(const bf16x8*)(Vs + (d * 16 + lr) * KVB + ((1 * 32 + lg * 8) ^ swz));
      o[d] = __builtin_amdgcn_mfma_f32_16x16x32_bf16(pf1, vf1, o[d], 0, 0, 0);
    }
    __builtin_amdgcn_s_setprio(0);
    __syncthreads();  // #2: all waves done reading Vs -> next tile may overwrite
  }

  // epilogue: total l per row, broadcast to o-row layout, divide, write bf16
  float lt = ls;
  lt += __shfl_xor(lt, 16);
  lt += __shfl_xor(lt, 32);
  float rinv[4];
#pragma unroll
  for (int b = 0; b < 4; ++b) rinv[b] = 1.0f / __shfl(lt, lg * 4 + b);
  const size_t q0 = (size_t)bb * 2048 + qt * 64 + w * 16;
#pragma unroll
  for (int d = 0; d < 8; ++d)
#pragma unroll
    for (int b = 0; b < 4; ++b) {
      float val = o[d][b] * rinv[b];
      O[(q0 + lg * 4 + b) * 2048 + h * 128 + d * 16 + lr] = (bf16_t)val;
    }
}

// ---------------------------------------------------------------- launch
extern "C" void kernel_launch(void* const* d_in, const int* in_sizes, int n_in,
                              void* d_out, int out_size, void* d_ws, size_t ws_size,
                              hipStream_t stream) {
  const float* hs = (const float*)d_in[0];
  const float* fc = (const float*)d_in[1];
  const float* fs = (const float*)d_in[2];
  const float* Wq = (const float*)d_in[3];
  const float* Wk = (const float*)d_in[4];
  const float* Wv = (const float*)d_in[5];
  const float* Wo = (const float*)d_in[6];
  float* out = (float*)d_out;

  char* ws = (char*)d_ws;
  bf16_t* hs_b = (bf16_t*)ws;                      // 16,777,216 B
  bf16_t* wcat = (bf16_t*)(ws + 16777216);         // 12,582,912 B (3072x2048)
  bf16_t* wo_b = (bf16_t*)(ws + 29360128);         //  8,388,608 B
  float* qkv = (float*)(ws + 37748736);            // 50,331,648 B (4096x3072)
  bf16_t* qr = (bf16_t*)(ws + 88080384);           // 16,777,216 B
  bf16_t* kr = (bf16_t*)(ws + 104857600);          //  4,194,304 B
  bf16_t* vt = (bf16_t*)(ws + 109051904);          //  4,194,304 B
  bf16_t* ao = (bf16_t*)(ws + 113246208);          // 16,777,216 B  (total ~124 MB)

  cvt_kernel<<<8388608 / 8 / 256, 256, 0, stream>>>(hs, hs_b, 8388608 / 8);
  cvt_kernel<<<4194304 / 8 / 256, 256, 0, stream>>>(Wq, wcat, 4194304 / 8);
  cvt_kernel<<<1048576 / 8 / 256, 256, 0, stream>>>(Wk, wcat + 4194304, 1048576 / 8);
  cvt_kernel<<<1048576 / 8 / 256, 256, 0, stream>>>(Wv, wcat + 5242880, 1048576 / 8);
  cvt_kernel<<<4194304 / 8 / 256, 256, 0, stream>>>(Wo, wo_b, 4194304 / 8);

  dim3 g1(3072 / BN, 4096 / BM);
  gemm_bt<<<g1, 256, 0, stream>>>(hs_b, wcat, qkv, 4096, 3072, 2048);

  rope_kernel<<<4096, 256, 0, stream>>>(qkv, fc, fs, qr, 16, 4, 0);
  rope_kernel<<<1024, 256, 0, stream>>>(qkv, fc, fs, kr, 4, 2, 2048);
  vt_kernel<<<256, 256, 0, stream>>>(qkv, vt);

  attn_kernel<<<1024, 256, 0, stream>>>(qr, kr, vt, ao);

  dim3 g2(2048 / BN, 4096 / BM);
  gemm_bt<<<g2, 256, 0, stream>>>(ao, wo_b, out, 4096, 2048, 2048);
}

// Round 6
// 261.248 us; speedup vs baseline: 1.5815x; 1.1464x over previous
//
#include <hip/hip_runtime.h>

typedef __bf16 bf16_t;
typedef bf16_t bf16x8 __attribute__((ext_vector_type(8)));
typedef bf16_t bf16x4 __attribute__((ext_vector_type(4)));
typedef bf16_t bf16x2 __attribute__((ext_vector_type(2)));
typedef float f32x4 __attribute__((ext_vector_type(4)));
typedef unsigned int u32x4 __attribute__((ext_vector_type(4)));

typedef const __attribute__((address_space(1))) void* as1_cvp;
typedef __attribute__((address_space(3))) void* as3_vp;

__device__ __forceinline__ void gload16(const void* g, void* l) {
  __builtin_amdgcn_global_load_lds((as1_cvp)g, (as3_vp)l, 16, 0, 0);
}

// ---------------------------------------------------------------- convert f32 -> bf16
__global__ __launch_bounds__(256) void cvt_kernel(const float* __restrict__ src,
                                                  bf16_t* __restrict__ dst, int n8) {
  int i = blockIdx.x * 256 + threadIdx.x;
  if (i >= n8) return;
  int idx = i * 8;
  float4 a = *(const float4*)(src + idx);
  float4 b = *(const float4*)(src + idx + 4);
  bf16x8 o;
  o[0] = (bf16_t)a.x; o[1] = (bf16_t)a.y; o[2] = (bf16_t)a.z; o[3] = (bf16_t)a.w;
  o[4] = (bf16_t)b.x; o[5] = (bf16_t)b.y; o[6] = (bf16_t)b.z; o[7] = (bf16_t)b.w;
  *(bf16x8*)(dst + idx) = o;
}

#define BM 128
#define BN 128
#define BK 64

// ---------------------------------------------------------------- GEMM  C = A * B^T (f32 out)
__global__ __launch_bounds__(256, 2) void gemm_bt(const bf16_t* __restrict__ A,
                                                  const bf16_t* __restrict__ B,
                                                  float* __restrict__ C,
                                                  int M, int N, int K) {
  __shared__ alignas(16) bf16_t As[BM * BK];
  __shared__ alignas(16) bf16_t Bs[BN * BK];
  const int t = threadIdx.x;
  const int lane = t & 63, w = t >> 6;
  const int wm = w >> 1, wn = w & 1;
  const int lr = lane & 15, lg = lane >> 4;
  const int m0 = blockIdx.y * BM, n0 = blockIdx.x * BN;
  const int srow = t >> 3, scol = (t & 7) * 8;

  f32x4 acc[4][4] = {};

  for (int kb = 0; kb < K; kb += BK) {
    __syncthreads();
#pragma unroll
    for (int i = 0; i < 4; ++i) {
      gload16(A + (size_t)(m0 + srow + 32 * i) * K + kb + scol, As + i * 2048 + t * 8);
      gload16(B + (size_t)(n0 + srow + 32 * i) * K + kb + scol, Bs + i * 2048 + t * 8);
    }
    __syncthreads();
#pragma unroll
    for (int kk = 0; kk < 2; ++kk) {
      const int ko = kk * 32 + lg * 8;
      bf16x8 af[4], bfr[4];
#pragma unroll
      for (int r = 0; r < 4; ++r)
        af[r] = *(const bf16x8*)(As + (wm * 64 + r * 16 + lr) * BK + ko);
#pragma unroll
      for (int c = 0; c < 4; ++c)
        bfr[c] = *(const bf16x8*)(Bs + (wn * 64 + c * 16 + lr) * BK + ko);
#pragma unroll
      for (int r = 0; r < 4; ++r)
#pragma unroll
        for (int c = 0; c < 4; ++c)
          acc[r][c] = __builtin_amdgcn_mfma_f32_16x16x32_bf16(af[r], bfr[c], acc[r][c], 0, 0, 0);
    }
  }
#pragma unroll
  for (int r = 0; r < 4; ++r)
#pragma unroll
    for (int c = 0; c < 4; ++c)
#pragma unroll
      for (int b = 0; b < 4; ++b)
        C[(size_t)(m0 + wm * 64 + r * 16 + lg * 4 + b) * N + n0 + wn * 64 + c * 16 + lr] =
            acc[r][c][b];
}

// ---------------------------------------------------------------- fused QKV GEMM + RoPE + relayout
// A: hs bf16 (4096 x 2048), B: wcat bf16 (3072 x 2048).
// Each BN=128 N-tile is exactly one head: heads 0-15 -> qr (rope),
// 16-19 -> kr (rope), 20-23 -> vt (transposed, no rope).
__global__ __launch_bounds__(256, 2) void gemm_qkv(const bf16_t* __restrict__ A,
                                                   const bf16_t* __restrict__ B,
                                                   const float* __restrict__ cs,
                                                   const float* __restrict__ sn,
                                                   bf16_t* __restrict__ qr,
                                                   bf16_t* __restrict__ kr,
                                                   bf16_t* __restrict__ vt) {
  __shared__ alignas(16) bf16_t As[BM * BK];
  __shared__ alignas(16) bf16_t Bs[BN * BK];
  const int K = 2048;
  const int t = threadIdx.x;
  const int lane = t & 63, w = t >> 6;
  const int wm = w >> 1, wn = w & 1;
  const int lr = lane & 15, lg = lane >> 4;
  const int m0 = blockIdx.y * BM, n0 = blockIdx.x * BN;
  const int srow = t >> 3, scol = (t & 7) * 8;

  f32x4 acc[4][4] = {};

  for (int kb = 0; kb < K; kb += BK) {
    __syncthreads();
#pragma unroll
    for (int i = 0; i < 4; ++i) {
      gload16(A + (size_t)(m0 + srow + 32 * i) * K + kb + scol, As + i * 2048 + t * 8);
      gload16(B + (size_t)(n0 + srow + 32 * i) * K + kb + scol, Bs + i * 2048 + t * 8);
    }
    __syncthreads();
#pragma unroll
    for (int kk = 0; kk < 2; ++kk) {
      const int ko = kk * 32 + lg * 8;
      bf16x8 af[4], bfr[4];
#pragma unroll
      for (int r = 0; r < 4; ++r)
        af[r] = *(const bf16x8*)(As + (wm * 64 + r * 16 + lr) * BK + ko);
#pragma unroll
      for (int c = 0; c < 4; ++c)
        bfr[c] = *(const bf16x8*)(Bs + (wn * 64 + c * 16 + lr) * BK + ko);
#pragma unroll
      for (int r = 0; r < 4; ++r)
#pragma unroll
        for (int c = 0; c < 4; ++c)
          acc[r][c] = __builtin_amdgcn_mfma_f32_16x16x32_bf16(af[r], bfr[c], acc[r][c], 0, 0, 0);
    }
  }

  // epilogue: D layout row=(lane>>4)*4+b, col=lane&15 within 16x16 frag
  const int head = n0 >> 7;               // one head per N-tile
  const int bb2 = m0 >> 11;               // batch
  const int sbase = (m0 & 2047) + wm * 64 + lg * 4;  // + r*16 + b -> token s
  if (head < 20) {
    // rope pairs (2d, 2d+1) live in adjacent lanes (lr parity)
    bf16_t* dst = (head < 16) ? qr + (size_t)(bb2 * 16 + head) * 2048 * 128
                              : kr + (size_t)(bb2 * 4 + (head - 16)) * 2048 * 128;
    const bool evn = (lr & 1) == 0;
#pragma unroll
    for (int r = 0; r < 4; ++r)
#pragma unroll
      for (int c = 0; c < 4; ++c) {
        const int cw = wn * 64 + c * 16 + lr;   // within-head col
        const int dix = cw >> 1;
#pragma unroll
        for (int b = 0; b < 4; ++b) {
          const int s = sbase + r * 16 + b;
          float own = acc[r][c][b];
          float prt = __shfl_xor(own, 1);       // partner (all lanes execute)
          if (evn) {                            // even lane holds x_e, prt = x_o
            float cc = cs[s * 64 + dix];
            float ssn = sn[s * 64 + dix];
            bf16x2 pr;
            pr[0] = (bf16_t)(own * cc - prt * ssn);
            pr[1] = (bf16_t)(own * ssn + prt * cc);
            *(bf16x2*)(dst + (size_t)s * 128 + cw) = pr;
          }
        }
      }
  } else {
    // V: write transposed (d-major): vt[(bb*4+vh)*128*2048 + d*2048 + s]
    bf16_t* dst = vt + (size_t)(bb2 * 4 + (head - 20)) * 128 * 2048;
#pragma unroll
    for (int r = 0; r < 4; ++r)
#pragma unroll
      for (int c = 0; c < 4; ++c) {
        const int cw = wn * 64 + c * 16 + lr;
        const int s = sbase + r * 16;
        bf16x4 v4;
#pragma unroll
        for (int b = 0; b < 4; ++b) v4[b] = (bf16_t)acc[r][c][b];
        *(bf16x4*)(dst + (size_t)cw * 2048 + s) = v4;
      }
  }
}

// ---------------------------------------------------------------- flash attention
// Q:(B,NH,S,HD) K:(B,NKV,S,HD) Vt:(B,NKV,HD,S) bf16 -> O:(B*S, H) bf16
// 4 waves/block, 16 q-rows/wave (QBLK=64). 32KB LDS (K single + V single) ->
// 4 blocks/CU, grid 1024 = exact packing (no tail). K(t+1) prefetched
// global->REGISTERS during tile t (T14), ds_written to Ks between barriers;
// V(t+1) staged via global_load_lds after the PV barrier (covered by next
// QK^T+softmax). Swapped QK^T, in-register softmax, shfl P-exchange.
// XOR-swizzled K/V (rule #21). T13 defer-rescale, T5 setprio, T1 XCD swizzle.
#define KVB 64
__global__ __launch_bounds__(256, 4) void attn_kernel(const bf16_t* __restrict__ Q,
                                                      const bf16_t* __restrict__ Kg,
                                                      const bf16_t* __restrict__ Vg,
                                                      bf16_t* __restrict__ O) {
  __shared__ alignas(16) bf16_t Ks[KVB * 128];   // 16KB [key][d], swizzled
  __shared__ alignas(16) bf16_t Vs[128 * KVB];   // 16KB [d][key], swizzled
  const int t = threadIdx.x;
  const int lane = t & 63, w = t >> 6;
  const int lr = lane & 15, lg = lane >> 4;
  const int swz = (lr & 7) * 8;
  // XCD-aware bijective swizzle (1024 % 8 == 0): each XCD owns one (bb,kvh)
  const int bid = ((blockIdx.x & 7) << 7) | (blockIdx.x >> 3);
  const int qt = bid & 31;
  const int h = (bid >> 5) & 15;
  const int bb = bid >> 9;
  const int kvh = h >> 2;

  const bf16_t* Qh = Q + (((size_t)bb * 16 + h) * 2048 + qt * 64 + w * 16) * 128;
  const bf16_t* Kh = Kg + ((size_t)bb * 4 + kvh) * 2048 * 128;
  const bf16_t* Vh = Vg + ((size_t)bb * 4 + kvh) * 128 * 2048;

  const int krow = t >> 4;                       // 0..15
  const int kcs = ((t & 15) ^ (krow & 7)) * 8;   // pre-swizzled col chunk (128-elem row)
  const int vrow = t >> 3;                       // 0..31
  const int vcs = ((t & 7) ^ (vrow & 7)) * 8;    // pre-swizzled col chunk (64-elem row)

  // hoist Q fragments; used as the MFMA *B* operand (swapped QK^T)
  bf16x8 qf[4];
#pragma unroll
  for (int kc = 0; kc < 4; ++kc)
    qf[kc] = *(const bf16x8*)(Qh + lr * 128 + kc * 32 + lg * 8);

  f32x4 o[8] = {};
  float m2 = -1e30f;  // running max for row q=lr
  float ls = 0.f;     // per-lane partial sum (16 k-slots)
  const float sm = 0.08838834764831845f * 1.44269504088896f;  // 1/sqrt(128)*log2(e)

  bf16x8 kreg[4];  // K(t+1) register prefetch

#define KREG_LOAD(kb)                                                                   \
  _Pragma("unroll") for (int i = 0; i < 4; ++i)                                         \
    kreg[i] = *(const bf16x8*)(Kh + (size_t)((kb) + i * 16 + krow) * 128 + kcs);
#define KDS_WRITE()                                                                     \
  _Pragma("unroll") for (int i = 0; i < 4; ++i)                                         \
    *(bf16x8*)(Ks + i * 2048 + t * 8) = kreg[i];
#define STAGE_V(kb)                                                                     \
  _Pragma("unroll") for (int i = 0; i < 4; ++i)                                         \
    gload16(Vh + (size_t)(i * 32 + vrow) * 2048 + (kb) + vcs, Vs + i * 2048 + t * 8);

  // prologue: V(0) in flight; K(0) -> regs -> LDS; K(1) in flight
  STAGE_V(0);
  KREG_LOAD(0);
  KDS_WRITE();
  KREG_LOAD(KVB);
  __syncthreads();  // Ks=K(0) visible; V(0) drained

  for (int tt = 0; tt < 32; ++tt) {
    // a) swapped QK^T: D[k][q] -> lane(lr,lg) holds P[q=lr][k=cg*16+lg*4+b]
    f32x4 sc[4];
    __builtin_amdgcn_s_setprio(1);
#pragma unroll
    for (int cg = 0; cg < 4; ++cg) {
      f32x4 a = {};
#pragma unroll
      for (int kc = 0; kc < 4; ++kc) {
        bf16x8 kf = *(const bf16x8*)(Ks + (cg * 16 + lr) * 128 + ((kc * 32 + lg * 8) ^ swz));
        a = __builtin_amdgcn_mfma_f32_16x16x32_bf16(kf, qf[kc], a, 0, 0, 0);
      }
      sc[cg] = a * sm;  // log2 units
    }
    __builtin_amdgcn_s_setprio(0);

    // b) in-register online softmax (row q=lr spread over 4 lg lanes)
    float mx = fmaxf(fmaxf(fmaxf(sc[0][0], sc[0][1]), fmaxf(sc[0][2], sc[0][3])),
                     fmaxf(fmaxf(sc[1][0], sc[1][1]), fmaxf(sc[1][2], sc[1][3])));
    mx = fmaxf(mx, fmaxf(fmaxf(fmaxf(sc[2][0], sc[2][1]), fmaxf(sc[2][2], sc[2][3])),
                         fmaxf(fmaxf(sc[3][0], sc[3][1]), fmaxf(sc[3][2], sc[3][3]))));
    mx = fmaxf(mx, __shfl_xor(mx, 16));
    mx = fmaxf(mx, __shfl_xor(mx, 32));

    if (__any(mx > m2 + 8.0f)) {  // T13 defer-rescale
      float mn = fmaxf(m2, mx);
      float resc = exp2f(m2 - mn);
      m2 = mn;
      ls *= resc;
      float rb[4];
#pragma unroll
      for (int b = 0; b < 4; ++b) rb[b] = __shfl(resc, lg * 4 + b);
#pragma unroll
      for (int d = 0; d < 8; ++d)
#pragma unroll
        for (int b = 0; b < 4; ++b) o[d][b] *= rb[b];
    }
#pragma unroll
    for (int cg = 0; cg < 4; ++cg)
#pragma unroll
      for (int b = 0; b < 4; ++b) {
        float p = exp2f(sc[cg][b] - m2);
        sc[cg][b] = p;
        ls += p;
      }

    // pack bf16 pairs + redistribute to A-fragment layout (16 shfl + selects)
    unsigned W[8];
#pragma unroll
    for (int cg = 0; cg < 4; ++cg)
#pragma unroll
      for (int hh2 = 0; hh2 < 2; ++hh2) {
        bf16x2 pr = {(bf16_t)sc[cg][2 * hh2], (bf16_t)sc[cg][2 * hh2 + 1]};
        W[cg * 2 + hh2] = __builtin_bit_cast(unsigned, pr);
      }
    u32x4 pw[2];
#pragma unroll
    for (int kk = 0; kk < 2; ++kk)
#pragma unroll
      for (int m = 0; m < 4; ++m) {
        int srcl = lr + 16 * (2 * (lg & 1) + (m >> 1));
        int t0 = __shfl((int)W[(2 * kk) * 2 + (m & 1)], srcl);
        int t1 = __shfl((int)W[(2 * kk + 1) * 2 + (m & 1)], srcl);
        pw[kk][m] = (unsigned)((lg & 2) ? t1 : t0);
      }
    bf16x8 pf0 = __builtin_bit_cast(bf16x8, pw[0]);
    bf16x8 pf1 = __builtin_bit_cast(bf16x8, pw[1]);

    __syncthreads();  // c) all QK^T reads done (Ks writable); V(t)/kreg arrived

    if (tt < 31) { KDS_WRITE(); }  // Ks <- K(t+1) while PV runs on Vs

    // d) PV from Vs
    __builtin_amdgcn_s_setprio(1);
#pragma unroll
    for (int d = 0; d < 8; ++d) {
      bf16x8 vf0 = *(const bf16x8*)(Vs + (d * 16 + lr) * KVB + ((lg * 8) ^ swz));
      o[d] = __builtin_amdgcn_mfma_f32_16x16x32_bf16(pf0, vf0, o[d], 0, 0, 0);
      bf16x8 vf1 = *(const bf16x8*)(Vs + (d * 16 + lr) * KVB + ((32 + lg * 8) ^ swz));
      o[d] = __builtin_amdgcn_mfma_f32_16x16x32_bf16(pf1, vf1, o[d], 0, 0, 0);
    }
    __builtin_amdgcn_s_setprio(0);
    __syncthreads();  // e) PV done (Vs writable); Ks writes visible

    if (tt < 31) { STAGE_V((tt + 1) * KVB); }     // V(t+1) -> covered by next a+b
    if (tt < 30) { KREG_LOAD((tt + 2) * KVB); }   // K(t+2) -> regs
  }

  // epilogue: total l per row, divide, write (B*S, H) bf16
  float lt = ls;
  lt += __shfl_xor(lt, 16);
  lt += __shfl_xor(lt, 32);
  float rinv[4];
#pragma unroll
  for (int b = 0; b < 4; ++b) rinv[b] = 1.0f / __shfl(lt, lg * 4 + b);
  const size_t q0 = (size_t)bb * 2048 + qt * 64 + w * 16;
#pragma unroll
  for (int d = 0; d < 8; ++d)
#pragma unroll
    for (int b = 0; b < 4; ++b) {
      float val = o[d][b] * rinv[b];
      O[(q0 + lg * 4 + b) * 2048 + h * 128 + d * 16 + lr] = (bf16_t)val;
    }
}

// ---------------------------------------------------------------- launch
extern "C" void kernel_launch(void* const* d_in, const int* in_sizes, int n_in,
                              void* d_out, int out_size, void* d_ws, size_t ws_size,
                              hipStream_t stream) {
  const float* hs = (const float*)d_in[0];
  const float* fc = (const float*)d_in[1];
  const float* fs = (const float*)d_in[2];
  const float* Wq = (const float*)d_in[3];
  const float* Wk = (const float*)d_in[4];
  const float* Wv = (const float*)d_in[5];
  const float* Wo = (const float*)d_in[6];
  float* out = (float*)d_out;

  char* ws = (char*)d_ws;
  bf16_t* hs_b = (bf16_t*)ws;                      // 16,777,216 B
  bf16_t* wcat = (bf16_t*)(ws + 16777216);         // 12,582,912 B (3072x2048)
  bf16_t* wo_b = (bf16_t*)(ws + 29360128);         //  8,388,608 B
  bf16_t* qr = (bf16_t*)(ws + 37748736);           // 16,777,216 B (B,16,S,128)
  bf16_t* kr = (bf16_t*)(ws + 54525952);           //  4,194,304 B (B,4,S,128)
  bf16_t* vt = (bf16_t*)(ws + 58720256);           //  4,194,304 B (B,4,128,S)
  bf16_t* ao = (bf16_t*)(ws + 62914560);           // 16,777,216 B  (total ~76 MB)

  cvt_kernel<<<8388608 / 8 / 256, 256, 0, stream>>>(hs, hs_b, 8388608 / 8);
  cvt_kernel<<<4194304 / 8 / 256, 256, 0, stream>>>(Wq, wcat, 4194304 / 8);
  cvt_kernel<<<1048576 / 8 / 256, 256, 0, stream>>>(Wk, wcat + 4194304, 1048576 / 8);
  cvt_kernel<<<1048576 / 8 / 256, 256, 0, stream>>>(Wv, wcat + 5242880, 1048576 / 8);
  cvt_kernel<<<4194304 / 8 / 256, 256, 0, stream>>>(Wo, wo_b, 4194304 / 8);

  dim3 g1(3072 / BN, 4096 / BM);
  gemm_qkv<<<g1, 256, 0, stream>>>(hs_b, wcat, fc, fs, qr, kr, vt);

  attn_kernel<<<1024, 256, 0, stream>>>(qr, kr, vt, ao);

  dim3 g2(2048 / BN, 4096 / BM);
  gemm_bt<<<g2, 256, 0, stream>>>(ao, wo_b, out, 4096, 2048, 2048);
}

// Round 7
// 244.578 us; speedup vs baseline: 1.6893x; 1.0682x over previous
//
#include <hip/hip_runtime.h>

typedef __bf16 bf16_t;
typedef bf16_t bf16x8 __attribute__((ext_vector_type(8)));
typedef bf16_t bf16x4 __attribute__((ext_vector_type(4)));
typedef bf16_t bf16x2 __attribute__((ext_vector_type(2)));
typedef float f32x4 __attribute__((ext_vector_type(4)));
typedef unsigned int u32x4 __attribute__((ext_vector_type(4)));

typedef const __attribute__((address_space(1))) void* as1_cvp;
typedef __attribute__((address_space(3))) void* as3_vp;

__device__ __forceinline__ void gload16(const void* g, void* l) {
  __builtin_amdgcn_global_load_lds((as1_cvp)g, (as3_vp)l, 16, 0, 0);
}

// ---------------------------------------------------------------- convert f32 -> bf16
__global__ __launch_bounds__(256) void cvt_kernel(const float* __restrict__ src,
                                                  bf16_t* __restrict__ dst, int n8) {
  int i = blockIdx.x * 256 + threadIdx.x;
  if (i >= n8) return;
  int idx = i * 8;
  float4 a = *(const float4*)(src + idx);
  float4 b = *(const float4*)(src + idx + 4);
  bf16x8 o;
  o[0] = (bf16_t)a.x; o[1] = (bf16_t)a.y; o[2] = (bf16_t)a.z; o[3] = (bf16_t)a.w;
  o[4] = (bf16_t)b.x; o[5] = (bf16_t)b.y; o[6] = (bf16_t)b.z; o[7] = (bf16_t)b.w;
  *(bf16x8*)(dst + idx) = o;
}

#define BM 128
#define BN 128
#define BK 64

// ---------------------------------------------------------------- GEMM  C = A * B^T (f32 out)
__global__ __launch_bounds__(256, 2) void gemm_bt(const bf16_t* __restrict__ A,
                                                  const bf16_t* __restrict__ B,
                                                  float* __restrict__ C,
                                                  int M, int N, int K) {
  __shared__ alignas(16) bf16_t As[BM * BK];
  __shared__ alignas(16) bf16_t Bs[BN * BK];
  const int t = threadIdx.x;
  const int lane = t & 63, w = t >> 6;
  const int wm = w >> 1, wn = w & 1;
  const int lr = lane & 15, lg = lane >> 4;
  const int m0 = blockIdx.y * BM, n0 = blockIdx.x * BN;
  const int srow = t >> 3, scol = (t & 7) * 8;

  f32x4 acc[4][4] = {};

  for (int kb = 0; kb < K; kb += BK) {
    __syncthreads();
#pragma unroll
    for (int i = 0; i < 4; ++i) {
      gload16(A + (size_t)(m0 + srow + 32 * i) * K + kb + scol, As + i * 2048 + t * 8);
      gload16(B + (size_t)(n0 + srow + 32 * i) * K + kb + scol, Bs + i * 2048 + t * 8);
    }
    __syncthreads();
#pragma unroll
    for (int kk = 0; kk < 2; ++kk) {
      const int ko = kk * 32 + lg * 8;
      bf16x8 af[4], bfr[4];
#pragma unroll
      for (int r = 0; r < 4; ++r)
        af[r] = *(const bf16x8*)(As + (wm * 64 + r * 16 + lr) * BK + ko);
#pragma unroll
      for (int c = 0; c < 4; ++c)
        bfr[c] = *(const bf16x8*)(Bs + (wn * 64 + c * 16 + lr) * BK + ko);
#pragma unroll
      for (int r = 0; r < 4; ++r)
#pragma unroll
        for (int c = 0; c < 4; ++c)
          acc[r][c] = __builtin_amdgcn_mfma_f32_16x16x32_bf16(af[r], bfr[c], acc[r][c], 0, 0, 0);
    }
  }
#pragma unroll
  for (int r = 0; r < 4; ++r)
#pragma unroll
    for (int c = 0; c < 4; ++c)
#pragma unroll
      for (int b = 0; b < 4; ++b)
        C[(size_t)(m0 + wm * 64 + r * 16 + lg * 4 + b) * N + n0 + wn * 64 + c * 16 + lr] =
            acc[r][c][b];
}

// ---------------------------------------------------------------- fused QKV GEMM + RoPE + relayout
// A: hs bf16 (4096 x 2048), B: wcat bf16 (3072 x 2048).
// Each BN=128 N-tile is exactly one head: heads 0-15 -> qr (rope),
// 16-19 -> kr (rope), 20-23 -> vt (transposed, no rope).
__global__ __launch_bounds__(256, 2) void gemm_qkv(const bf16_t* __restrict__ A,
                                                   const bf16_t* __restrict__ B,
                                                   const float* __restrict__ cs,
                                                   const float* __restrict__ sn,
                                                   bf16_t* __restrict__ qr,
                                                   bf16_t* __restrict__ kr,
                                                   bf16_t* __restrict__ vt) {
  __shared__ alignas(16) bf16_t As[BM * BK];
  __shared__ alignas(16) bf16_t Bs[BN * BK];
  const int K = 2048;
  const int t = threadIdx.x;
  const int lane = t & 63, w = t >> 6;
  const int wm = w >> 1, wn = w & 1;
  const int lr = lane & 15, lg = lane >> 4;
  const int m0 = blockIdx.y * BM, n0 = blockIdx.x * BN;
  const int srow = t >> 3, scol = (t & 7) * 8;

  f32x4 acc[4][4] = {};

  for (int kb = 0; kb < K; kb += BK) {
    __syncthreads();
#pragma unroll
    for (int i = 0; i < 4; ++i) {
      gload16(A + (size_t)(m0 + srow + 32 * i) * K + kb + scol, As + i * 2048 + t * 8);
      gload16(B + (size_t)(n0 + srow + 32 * i) * K + kb + scol, Bs + i * 2048 + t * 8);
    }
    __syncthreads();
#pragma unroll
    for (int kk = 0; kk < 2; ++kk) {
      const int ko = kk * 32 + lg * 8;
      bf16x8 af[4], bfr[4];
#pragma unroll
      for (int r = 0; r < 4; ++r)
        af[r] = *(const bf16x8*)(As + (wm * 64 + r * 16 + lr) * BK + ko);
#pragma unroll
      for (int c = 0; c < 4; ++c)
        bfr[c] = *(const bf16x8*)(Bs + (wn * 64 + c * 16 + lr) * BK + ko);
#pragma unroll
      for (int r = 0; r < 4; ++r)
#pragma unroll
        for (int c = 0; c < 4; ++c)
          acc[r][c] = __builtin_amdgcn_mfma_f32_16x16x32_bf16(af[r], bfr[c], acc[r][c], 0, 0, 0);
    }
  }

  // epilogue: D layout row=(lane>>4)*4+b, col=lane&15 within 16x16 frag
  const int head = n0 >> 7;               // one head per N-tile
  const int bb2 = m0 >> 11;               // batch
  const int sbase = (m0 & 2047) + wm * 64 + lg * 4;  // + r*16 + b -> token s
  if (head < 20) {
    // rope pairs (2d, 2d+1) live in adjacent lanes (lr parity)
    bf16_t* dst = (head < 16) ? qr + (size_t)(bb2 * 16 + head) * 2048 * 128
                              : kr + (size_t)(bb2 * 4 + (head - 16)) * 2048 * 128;
    const bool evn = (lr & 1) == 0;
#pragma unroll
    for (int r = 0; r < 4; ++r)
#pragma unroll
      for (int c = 0; c < 4; ++c) {
        const int cw = wn * 64 + c * 16 + lr;   // within-head col
        const int dix = cw >> 1;
#pragma unroll
        for (int b = 0; b < 4; ++b) {
          const int s = sbase + r * 16 + b;
          float own = acc[r][c][b];
          float prt = __shfl_xor(own, 1);       // partner (all lanes execute)
          if (evn) {                            // even lane holds x_e, prt = x_o
            float cc = cs[s * 64 + dix];
            float ssn = sn[s * 64 + dix];
            bf16x2 pr;
            pr[0] = (bf16_t)(own * cc - prt * ssn);
            pr[1] = (bf16_t)(own * ssn + prt * cc);
            *(bf16x2*)(dst + (size_t)s * 128 + cw) = pr;
          }
        }
      }
  } else {
    // V: write transposed (d-major): vt[(bb*4+vh)*128*2048 + d*2048 + s]
    bf16_t* dst = vt + (size_t)(bb2 * 4 + (head - 20)) * 128 * 2048;
#pragma unroll
    for (int r = 0; r < 4; ++r)
#pragma unroll
      for (int c = 0; c < 4; ++c) {
        const int cw = wn * 64 + c * 16 + lr;
        const int s = sbase + r * 16;
        bf16x4 v4;
#pragma unroll
        for (int b = 0; b < 4; ++b) v4[b] = (bf16_t)acc[r][c][b];
        *(bf16x4*)(dst + (size_t)cw * 2048 + s) = v4;
      }
  }
}

// ---------------------------------------------------------------- flash attention
// Q:(B,NH,S,HD) K:(B,NKV,S,HD) Vt:(B,NKV,HD,S) bf16 -> O:(B*S, H) bf16
// 4 waves/block, 32 q-rows/wave (QBLK=128, 2 row-groups): K/V fragments are
// reused across both row-groups -> LDS bytes per MFMA-FLOP halved (the round-6
// profile was LDS-BW-bound: 4 waves x 32KB/tile ~ 1540cy vs 620cy MFMA).
// K double-buffered via global_load_lds (2-phase), V single-buffered (staged at
// tile top, covered by QK^T+softmax). 48KB LDS, grid 512 = exact 2 blocks/CU.
// Swapped QK^T, in-register softmax, shfl P-exchange. XOR-swizzle (rule #21),
// T13 defer-rescale, T5 setprio, T1 XCD swizzle (each XCD owns one (bb,kvh)).
#define KVB 64
__global__ __launch_bounds__(256, 2) void attn_kernel(const bf16_t* __restrict__ Q,
                                                      const bf16_t* __restrict__ Kg,
                                                      const bf16_t* __restrict__ Vg,
                                                      bf16_t* __restrict__ O) {
  __shared__ alignas(16) bf16_t Ks[2][KVB * 128];  // 32KB [key][d], swizzled
  __shared__ alignas(16) bf16_t Vs[128 * KVB];     // 16KB [d][key], swizzled
  const int t = threadIdx.x;
  const int lane = t & 63, w = t >> 6;
  const int lr = lane & 15, lg = lane >> 4;
  const int swz = (lr & 7) * 8;
  // XCD-aware bijective swizzle (512 % 8 == 0): each XCD owns one (bb,kvh)
  const int bid = ((blockIdx.x & 7) << 6) | (blockIdx.x >> 3);
  const int qt = bid & 15;          // 16 q-tiles of 128 rows
  const int h = (bid >> 4) & 15;
  const int bb = bid >> 8;
  const int kvh = h >> 2;

  const bf16_t* Qh = Q + (((size_t)bb * 16 + h) * 2048 + qt * 128 + w * 32) * 128;
  const bf16_t* Kh = Kg + ((size_t)bb * 4 + kvh) * 2048 * 128;
  const bf16_t* Vh = Vg + ((size_t)bb * 4 + kvh) * 128 * 2048;

  const int krow = t >> 4;                       // 0..15
  const int kcs = ((t & 15) ^ (krow & 7)) * 8;   // pre-swizzled col chunk (128-elem row)
  const int vrow = t >> 3;                       // 0..31
  const int vcs = ((t & 7) ^ (vrow & 7)) * 8;    // pre-swizzled col chunk (64-elem row)

  // hoist Q fragments (2 row-groups); used as the MFMA *B* operand (swapped QK^T)
  bf16x8 qf[2][4];
#pragma unroll
  for (int rg = 0; rg < 2; ++rg)
#pragma unroll
    for (int kc = 0; kc < 4; ++kc)
      qf[rg][kc] = *(const bf16x8*)(Qh + (rg * 16 + lr) * 128 + kc * 32 + lg * 8);

  f32x4 o[2][8] = {};
  float m2[2] = {-1e30f, -1e30f};  // running max for row q=lr of each row-group
  float ls[2] = {0.f, 0.f};        // per-lane partial sums
  const float sm = 0.08838834764831845f * 1.44269504088896f;  // 1/sqrt(128)*log2(e)

#define STAGE_K(buf, kb)                                                                  \
  _Pragma("unroll") for (int i = 0; i < 4; ++i)                                           \
    gload16(Kh + (size_t)((kb) + i * 16 + krow) * 128 + kcs, &Ks[buf][i * 2048 + t * 8]);
#define STAGE_V(kb)                                                                       \
  _Pragma("unroll") for (int i = 0; i < 4; ++i)                                           \
    gload16(Vh + (size_t)(i * 32 + vrow) * 2048 + (kb) + vcs, Vs + i * 2048 + t * 8);

  STAGE_K(0, 0);
  __syncthreads();  // K(0) ready

  for (int tt = 0; tt < 32; ++tt) {
    const int cur = tt & 1;
    STAGE_V(tt * KVB);                                  // V(t): covered by QK^T+softmax
    if (tt < 31) { STAGE_K(cur ^ 1, (tt + 1) * KVB); }  // K(t+1): covered by full tile
    const bf16_t* Kc = Ks[cur];

    // a) swapped QK^T: lane(lr,lg) holds P[q=lr][k=cg*16+lg*4+b] per row-group
    f32x4 sc[2][4];
    __builtin_amdgcn_s_setprio(1);
#pragma unroll
    for (int cg = 0; cg < 4; ++cg) {
      f32x4 a0 = {}, a1 = {};
#pragma unroll
      for (int kc = 0; kc < 4; ++kc) {
        bf16x8 kf = *(const bf16x8*)(Kc + (cg * 16 + lr) * 128 + ((kc * 32 + lg * 8) ^ swz));
        a0 = __builtin_amdgcn_mfma_f32_16x16x32_bf16(kf, qf[0][kc], a0, 0, 0, 0);
        a1 = __builtin_amdgcn_mfma_f32_16x16x32_bf16(kf, qf[1][kc], a1, 0, 0, 0);
      }
      sc[0][cg] = a0 * sm;  // log2 units
      sc[1][cg] = a1 * sm;
    }
    __builtin_amdgcn_s_setprio(0);

    // b) in-register online softmax per row-group
    float mx[2];
#pragma unroll
    for (int rg = 0; rg < 2; ++rg) {
      float v = fmaxf(fmaxf(fmaxf(sc[rg][0][0], sc[rg][0][1]), fmaxf(sc[rg][0][2], sc[rg][0][3])),
                      fmaxf(fmaxf(sc[rg][1][0], sc[rg][1][1]), fmaxf(sc[rg][1][2], sc[rg][1][3])));
      v = fmaxf(v, fmaxf(fmaxf(fmaxf(sc[rg][2][0], sc[rg][2][1]), fmaxf(sc[rg][2][2], sc[rg][2][3])),
                         fmaxf(fmaxf(sc[rg][3][0], sc[rg][3][1]), fmaxf(sc[rg][3][2], sc[rg][3][3]))));
      v = fmaxf(v, __shfl_xor(v, 16));
      v = fmaxf(v, __shfl_xor(v, 32));
      mx[rg] = v;
    }
    if (__any((mx[0] > m2[0] + 8.0f) || (mx[1] > m2[1] + 8.0f))) {  // T13
#pragma unroll
      for (int rg = 0; rg < 2; ++rg) {
        float mn = fmaxf(m2[rg], mx[rg]);
        float resc = exp2f(m2[rg] - mn);
        m2[rg] = mn;
        ls[rg] *= resc;
        float rb[4];
#pragma unroll
        for (int b = 0; b < 4; ++b) rb[b] = __shfl(resc, lg * 4 + b);
#pragma unroll
        for (int d = 0; d < 8; ++d)
#pragma unroll
          for (int b = 0; b < 4; ++b) o[rg][d][b] *= rb[b];
      }
    }
    bf16x8 pf[2][2];
#pragma unroll
    for (int rg = 0; rg < 2; ++rg) {
#pragma unroll
      for (int cg = 0; cg < 4; ++cg)
#pragma unroll
        for (int b = 0; b < 4; ++b) {
          float p = exp2f(sc[rg][cg][b] - m2[rg]);
          sc[rg][cg][b] = p;
          ls[rg] += p;
        }
      // pack bf16 pairs + redistribute to A-fragment layout (16 shfl + selects)
      unsigned W[8];
#pragma unroll
      for (int cg = 0; cg < 4; ++cg)
#pragma unroll
        for (int hh2 = 0; hh2 < 2; ++hh2) {
          bf16x2 pr = {(bf16_t)sc[rg][cg][2 * hh2], (bf16_t)sc[rg][cg][2 * hh2 + 1]};
          W[cg * 2 + hh2] = __builtin_bit_cast(unsigned, pr);
        }
      u32x4 pw[2];
#pragma unroll
      for (int kk = 0; kk < 2; ++kk)
#pragma unroll
        for (int m = 0; m < 4; ++m) {
          int srcl = lr + 16 * (2 * (lg & 1) + (m >> 1));
          int t0 = __shfl((int)W[(2 * kk) * 2 + (m & 1)], srcl);
          int t1 = __shfl((int)W[(2 * kk + 1) * 2 + (m & 1)], srcl);
          pw[kk][m] = (unsigned)((lg & 2) ? t1 : t0);
        }
      pf[rg][0] = __builtin_bit_cast(bf16x8, pw[0]);
      pf[rg][1] = __builtin_bit_cast(bf16x8, pw[1]);
    }

    __syncthreads();  // c) QK^T reads done; V(t) and K(t+1) arrived (vmcnt drain)

    // d) PV from Vs: vf reused across both row-groups
    __builtin_amdgcn_s_setprio(1);
#pragma unroll
    for (int d = 0; d < 8; ++d) {
      bf16x8 vf0 = *(const bf16x8*)(Vs + (d * 16 + lr) * KVB + ((lg * 8) ^ swz));
      o[0][d] = __builtin_amdgcn_mfma_f32_16x16x32_bf16(pf[0][0], vf0, o[0][d], 0, 0, 0);
      o[1][d] = __builtin_amdgcn_mfma_f32_16x16x32_bf16(pf[1][0], vf0, o[1][d], 0, 0, 0);
      bf16x8 vf1 = *(const bf16x8*)(Vs + (d * 16 + lr) * KVB + ((32 + lg * 8) ^ swz));
      o[0][d] = __builtin_amdgcn_mfma_f32_16x16x32_bf16(pf[0][1], vf1, o[0][d], 0, 0, 0);
      o[1][d] = __builtin_amdgcn_mfma_f32_16x16x32_bf16(pf[1][1], vf1, o[1][d], 0, 0, 0);
    }
    __builtin_amdgcn_s_setprio(0);
    __syncthreads();  // e) PV done -> Vs writable next tile
  }

  // epilogue: total l per row, divide, write (B*S, H) bf16
  const size_t q0 = (size_t)bb * 2048 + qt * 128 + w * 32;
#pragma unroll
  for (int rg = 0; rg < 2; ++rg) {
    float lt = ls[rg];
    lt += __shfl_xor(lt, 16);
    lt += __shfl_xor(lt, 32);
    float rinv[4];
#pragma unroll
    for (int b = 0; b < 4; ++b) rinv[b] = 1.0f / __shfl(lt, lg * 4 + b);
#pragma unroll
    for (int d = 0; d < 8; ++d)
#pragma unroll
      for (int b = 0; b < 4; ++b) {
        float val = o[rg][d][b] * rinv[b];
        O[(q0 + rg * 16 + lg * 4 + b) * 2048 + h * 128 + d * 16 + lr] = (bf16_t)val;
      }
  }
}

// ---------------------------------------------------------------- launch
extern "C" void kernel_launch(void* const* d_in, const int* in_sizes, int n_in,
                              void* d_out, int out_size, void* d_ws, size_t ws_size,
                              hipStream_t stream) {
  const float* hs = (const float*)d_in[0];
  const float* fc = (const float*)d_in[1];
  const float* fs = (const float*)d_in[2];
  const float* Wq = (const float*)d_in[3];
  const float* Wk = (const float*)d_in[4];
  const float* Wv = (const float*)d_in[5];
  const float* Wo = (const float*)d_in[6];
  float* out = (float*)d_out;

  char* ws = (char*)d_ws;
  bf16_t* hs_b = (bf16_t*)ws;                      // 16,777,216 B
  bf16_t* wcat = (bf16_t*)(ws + 16777216);         // 12,582,912 B (3072x2048)
  bf16_t* wo_b = (bf16_t*)(ws + 29360128);         //  8,388,608 B
  bf16_t* qr = (bf16_t*)(ws + 37748736);           // 16,777,216 B (B,16,S,128)
  bf16_t* kr = (bf16_t*)(ws + 54525952);           //  4,194,304 B (B,4,S,128)
  bf16_t* vt = (bf16_t*)(ws + 58720256);           //  4,194,304 B (B,4,128,S)
  bf16_t* ao = (bf16_t*)(ws + 62914560);           // 16,777,216 B  (total ~76 MB)

  cvt_kernel<<<8388608 / 8 / 256, 256, 0, stream>>>(hs, hs_b, 8388608 / 8);
  cvt_kernel<<<4194304 / 8 / 256, 256, 0, stream>>>(Wq, wcat, 4194304 / 8);
  cvt_kernel<<<1048576 / 8 / 256, 256, 0, stream>>>(Wk, wcat + 4194304, 1048576 / 8);
  cvt_kernel<<<1048576 / 8 / 256, 256, 0, stream>>>(Wv, wcat + 5242880, 1048576 / 8);
  cvt_kernel<<<4194304 / 8 / 256, 256, 0, stream>>>(Wo, wo_b, 4194304 / 8);

  dim3 g1(3072 / BN, 4096 / BM);
  gemm_qkv<<<g1, 256, 0, stream>>>(hs_b, wcat, fc, fs, qr, kr, vt);

  attn_kernel<<<512, 256, 0, stream>>>(qr, kr, vt, ao);

  dim3 g2(2048 / BN, 4096 / BM);
  gemm_bt<<<g2, 256, 0, stream>>>(ao, wo_b, out, 4096, 2048, 2048);
}